// Round 2
// baseline (366.399 us; speedup 1.0000x reference)
//
#include <hip/hip_runtime.h>

// GaussianLikelihoodLoss: mean over (b,t) of d^T Sigma^{-1} d + log|Sigma|
// pred/target: [B,N,T] f32 ; cov: [B,N,N,T] f32 ; out: scalar f32
// B=1024, N=16, T=256.
//
// Per (b,t): 16x16 SPD solve via 2x2-BLOCKED Cholesky (8x8 blocks) with
// early register retirement:
//   chol(A) -> y1 = L_A^{-1} d1 -> W = B L_A^{-T} -> [drop L_A, y1]
//   S = C - W W^T               -> [drop W]
//   chol(S) -> y2 = L_S^{-1}(d2 - W y1)
// Peak live ~110 floats (vs ~155 for the monolithic version) so we can run
// 3 waves/SIMD (__launch_bounds__(256,3), VGPR cap ~168) without spilling.

#define B_ 1024
#define N_ 16
#define T_ 256

#define TIDX(i, j) ((i) * ((i) + 1) / 2 + (j))  // lower-triangle index, 8x8 -> 36

__global__ __launch_bounds__(256, 3) void gll_main(
    const float* __restrict__ pred,
    const float* __restrict__ targ,
    const float* __restrict__ cov,
    float* __restrict__ partial)
{
    const int b = blockIdx.x;      // one block per batch
    const int t = threadIdx.x;     // one thread per time step

    const size_t cbase = (size_t)b * N_ * N_ * T_ + t;
    const size_t pbase = (size_t)b * N_ * T_ + t;

    float logdet = 0.f;
    float quad   = 0.f;

    // ---------------- Phase A: A = cov[0:8,0:8] lower, chol in place --------
    float LA[36];
#pragma unroll
    for (int i = 0; i < 8; ++i)
#pragma unroll
        for (int j = 0; j <= i; ++j)
            LA[TIDX(i, j)] = __builtin_nontemporal_load(
                &cov[cbase + (size_t)(i * N_ + j) * T_]);

#pragma unroll
    for (int i = 0; i < 8; ++i) {
#pragma unroll
        for (int j = 0; j < i; ++j) {
            float s = LA[TIDX(i, j)];
#pragma unroll
            for (int k = 0; k < j; ++k)
                s -= LA[TIDX(i, k)] * LA[TIDX(j, k)];
            LA[TIDX(i, j)] = s * LA[TIDX(j, j)];   // * inv L_jj
        }
        float s = LA[TIDX(i, i)];
#pragma unroll
        for (int k = 0; k < i; ++k)
            s -= LA[TIDX(i, k)] * LA[TIDX(i, k)];
        logdet += __logf(s);
        LA[TIDX(i, i)] = rsqrtf(s);                // store 1/L_ii
    }

    // y1 = L_A^{-1} d1
    float y1[8];
#pragma unroll
    for (int i = 0; i < 8; ++i) {
        float s = __builtin_nontemporal_load(&pred[pbase + i * T_]) -
                  __builtin_nontemporal_load(&targ[pbase + i * T_]);
#pragma unroll
        for (int k = 0; k < i; ++k)
            s -= LA[TIDX(i, k)] * y1[k];
        y1[i] = s * LA[TIDX(i, i)];
        quad += y1[i] * y1[i];
    }

    // ---------------- Phase B: W = B L_A^{-T},  B = cov[8:16, 0:8] ----------
    float W[64];
#pragma unroll
    for (int r = 0; r < 8; ++r)
#pragma unroll
        for (int j = 0; j < 8; ++j)
            W[r * 8 + j] = __builtin_nontemporal_load(
                &cov[cbase + (size_t)((r + 8) * N_ + j) * T_]);

#pragma unroll
    for (int r = 0; r < 8; ++r) {
#pragma unroll
        for (int j = 0; j < 8; ++j) {
            float s = W[r * 8 + j];
#pragma unroll
            for (int k = 0; k < j; ++k)
                s -= W[r * 8 + k] * LA[TIDX(j, k)];
            W[r * 8 + j] = s * LA[TIDX(j, j)];
        }
    }

    // t2 = d2 - W y1   (after this, LA and y1 are dead)
    float t2[8];
#pragma unroll
    for (int r = 0; r < 8; ++r) {
        float s = __builtin_nontemporal_load(&pred[pbase + (r + 8) * T_]) -
                  __builtin_nontemporal_load(&targ[pbase + (r + 8) * T_]);
#pragma unroll
        for (int k = 0; k < 8; ++k)
            s -= W[r * 8 + k] * y1[k];
        t2[r] = s;
    }

    // ---------------- Phase C: S = C - W W^T (lower),  C = cov[8:16,8:16] --
    float S[36];
#pragma unroll
    for (int i = 0; i < 8; ++i)
#pragma unroll
        for (int j = 0; j <= i; ++j) {
            float s = __builtin_nontemporal_load(
                &cov[cbase + (size_t)((i + 8) * N_ + (j + 8)) * T_]);
#pragma unroll
            for (int k = 0; k < 8; ++k)
                s -= W[i * 8 + k] * W[j * 8 + k];
            S[TIDX(i, j)] = s;
        }
    // W dead from here.

    // ---------------- Phase D: chol(S), y2 = L_S^{-1} t2 --------------------
#pragma unroll
    for (int i = 0; i < 8; ++i) {
#pragma unroll
        for (int j = 0; j < i; ++j) {
            float s = S[TIDX(i, j)];
#pragma unroll
            for (int k = 0; k < j; ++k)
                s -= S[TIDX(i, k)] * S[TIDX(j, k)];
            S[TIDX(i, j)] = s * S[TIDX(j, j)];
        }
        float s = S[TIDX(i, i)];
#pragma unroll
        for (int k = 0; k < i; ++k)
            s -= S[TIDX(i, k)] * S[TIDX(i, k)];
        logdet += __logf(s);
        S[TIDX(i, i)] = rsqrtf(s);
    }

#pragma unroll
    for (int i = 0; i < 8; ++i) {
        float s = t2[i];
#pragma unroll
        for (int k = 0; k < i; ++k)
            s -= S[TIDX(i, k)] * t2[k];   // t2[k] already holds y2[k]
        t2[i] = s * S[TIDX(i, i)];
        quad += t2[i] * t2[i];
    }

    float val = quad + logdet;

    // block reduction: wave64 shuffle, then LDS across 4 waves
#pragma unroll
    for (int off = 32; off > 0; off >>= 1)
        val += __shfl_down(val, off, 64);

    __shared__ float sred[4];
    const int wave = threadIdx.x >> 6;
    const int lane = threadIdx.x & 63;
    if (lane == 0) sred[wave] = val;
    __syncthreads();
    if (threadIdx.x == 0)
        partial[b] = sred[0] + sred[1] + sred[2] + sred[3];
}

__global__ __launch_bounds__(256) void gll_reduce(
    const float* __restrict__ partial,
    float* __restrict__ out)
{
    float s = 0.f;
#pragma unroll
    for (int i = 0; i < B_ / 256; ++i)
        s += partial[threadIdx.x + i * 256];

#pragma unroll
    for (int off = 32; off > 0; off >>= 1)
        s += __shfl_down(s, off, 64);

    __shared__ float sred[4];
    const int wave = threadIdx.x >> 6;
    const int lane = threadIdx.x & 63;
    if (lane == 0) sred[wave] = s;
    __syncthreads();
    if (threadIdx.x == 0) {
        float tot = sred[0] + sred[1] + sred[2] + sred[3];
        out[0] = tot / (float)((size_t)B_ * T_);
    }
}

extern "C" void kernel_launch(void* const* d_in, const int* in_sizes, int n_in,
                              void* d_out, int out_size, void* d_ws, size_t ws_size,
                              hipStream_t stream) {
    const float* pred = (const float*)d_in[0];
    const float* targ = (const float*)d_in[1];
    const float* cov  = (const float*)d_in[2];
    float* out = (float*)d_out;
    float* partial = (float*)d_ws;   // B_ floats = 4 KB

    gll_main<<<B_, 256, 0, stream>>>(pred, targ, cov, partial);
    gll_reduce<<<1, 256, 0, stream>>>(partial, out);
}

// Round 3
// 352.006 us; speedup vs baseline: 1.0409x; 1.0409x over previous
//
#include <hip/hip_runtime.h>

// GaussianLikelihoodLoss: mean over (b,t) of d^T Sigma^{-1} d + log|Sigma|
// pred/target: [B,N,T] f32 ; cov: [B,N,N,T] f32 ; out: scalar f32
// B=1024, N=16, T=256. Per (b,t): 16x16 Cholesky in registers.
//
// R2 post-mortem: 2x2-blocked Cholesky + __launch_bounds__(256,3) regressed
// 30.6 -> 45.8 us (scratch spills from the VGPR cap). This monolithic
// version runs at ~5.7 TB/s effective (~90% of the 6.3 TB/s achievable
// ceiling) against a 174.6 MB minimum-traffic floor of 27.7 us. Memory-bound
// and within ~10% of roofline; the per-iteration measurement is dominated by
// ~321 us of harness poison fills.

#define B_ 1024
#define N_ 16
#define T_ 256
#define TRI (N_ * (N_ + 1) / 2)   // 136

__global__ __launch_bounds__(256) void gll_main(
    const float* __restrict__ pred,
    const float* __restrict__ targ,
    const float* __restrict__ cov,
    float* __restrict__ partial)
{
    const int b = blockIdx.x;      // one block per batch
    const int t = threadIdx.x;     // one thread per time step

    // diff vector, coalesced across t
    float d[N_];
    const size_t pbase = (size_t)b * N_ * T_ + t;
#pragma unroll
    for (int n = 0; n < N_; ++n)
        d[n] = pred[pbase + n * T_] - targ[pbase + n * T_];

    // lower triangle of cov[b,i,j,t]; each (i,j) is a contiguous 1KB row over t
    float L[TRI];
    const size_t cbase = (size_t)b * N_ * N_ * T_ + t;
#pragma unroll
    for (int i = 0; i < N_; ++i)
#pragma unroll
        for (int j = 0; j <= i; ++j)
            L[i * (i + 1) / 2 + j] = cov[cbase + (size_t)(i * N_ + j) * T_];

    // In-place Cholesky. Diagonal slots store 1/L_ii (rsqrt of pivot).
    // logdet = sum log(pivot_i)  (== 2*sum log L_ii)
    float logdet = 0.f;
#pragma unroll
    for (int i = 0; i < N_; ++i) {
#pragma unroll
        for (int j = 0; j < i; ++j) {
            float s = L[i * (i + 1) / 2 + j];
#pragma unroll
            for (int k = 0; k < j; ++k)
                s -= L[i * (i + 1) / 2 + k] * L[j * (j + 1) / 2 + k];
            L[i * (i + 1) / 2 + j] = s * L[j * (j + 1) / 2 + j]; // * invL_jj
        }
        float s = L[i * (i + 1) / 2 + i];
#pragma unroll
        for (int k = 0; k < i; ++k)
            s -= L[i * (i + 1) / 2 + k] * L[i * (i + 1) / 2 + k];
        logdet += __logf(s);
        L[i * (i + 1) / 2 + i] = rsqrtf(s);
    }

    // Forward solve L y = d (y overwrites d); quad = ||y||^2
    float quad = 0.f;
#pragma unroll
    for (int i = 0; i < N_; ++i) {
        float s = d[i];
#pragma unroll
        for (int k = 0; k < i; ++k)
            s -= L[i * (i + 1) / 2 + k] * d[k];
        float y = s * L[i * (i + 1) / 2 + i];
        d[i] = y;
        quad += y * y;
    }

    float val = quad + logdet;

    // block reduction: wave64 shuffle, then LDS across 4 waves
#pragma unroll
    for (int off = 32; off > 0; off >>= 1)
        val += __shfl_down(val, off, 64);

    __shared__ float sred[4];
    const int wave = threadIdx.x >> 6;
    const int lane = threadIdx.x & 63;
    if (lane == 0) sred[wave] = val;
    __syncthreads();
    if (threadIdx.x == 0)
        partial[b] = sred[0] + sred[1] + sred[2] + sred[3];
}

__global__ __launch_bounds__(256) void gll_reduce(
    const float* __restrict__ partial,
    float* __restrict__ out)
{
    float s = 0.f;
#pragma unroll
    for (int i = 0; i < B_ / 256; ++i)
        s += partial[threadIdx.x + i * 256];

#pragma unroll
    for (int off = 32; off > 0; off >>= 1)
        s += __shfl_down(s, off, 64);

    __shared__ float sred[4];
    const int wave = threadIdx.x >> 6;
    const int lane = threadIdx.x & 63;
    if (lane == 0) sred[wave] = s;
    __syncthreads();
    if (threadIdx.x == 0) {
        float tot = sred[0] + sred[1] + sred[2] + sred[3];
        out[0] = tot / (float)((size_t)B_ * T_);
    }
}

extern "C" void kernel_launch(void* const* d_in, const int* in_sizes, int n_in,
                              void* d_out, int out_size, void* d_ws, size_t ws_size,
                              hipStream_t stream) {
    const float* pred = (const float*)d_in[0];
    const float* targ = (const float*)d_in[1];
    const float* cov  = (const float*)d_in[2];
    float* out = (float*)d_out;
    float* partial = (float*)d_ws;   // B_ floats = 4 KB

    gll_main<<<B_, 256, 0, stream>>>(pred, targ, cov, partial);
    gll_reduce<<<1, 256, 0, stream>>>(partial, out);
}